// Round 1
// baseline (107.273 us; speedup 1.0000x reference)
//
#include <hip/hip_runtime.h>

#define BATCH   4
#define NPTS    4096      // 64*64 top-surface points per batch
#define MPTS    8192      // cloud points per batch
#define TPB     256
#define VPT     8         // points per thread (register tile)
#define MSPLIT  64        // dist1: chunks over M -> MLEN=128
#define NSPLIT  32        // dist2: chunks over N -> NLEN=128
#define MLEN    (MPTS / MSPLIT)           // 128
#define NLEN    (NPTS / NSPLIT)           // 128
#define D1_NBLK (NPTS / (TPB * VPT))      // 2
#define D2_MBLK (MPTS / (TPB * VPT))      // 4
#define D1_BLOCKS (BATCH * D1_NBLK * MSPLIT)  // 512
#define D2_BLOCKS (BATCH * D2_MBLK * NSPLIT)  // 512
#define BIGF    1.0e30f

#define PART1_ELEMS (MSPLIT * BATCH * NPTS)   // 1048576 floats (4 MB)
#define PART2_ELEMS (NSPLIT * BATCH * MPTS)   // 1048576 floats (4 MB)
#define VQ_POINTS   (BATCH * NPTS)            // 16384 float4
#define PQ_POINTS   (BATCH * MPTS)            // 32768 float4

// reduce: 1 point per thread -> plenty of blocks to stream 8 MB at full BW
#define R1_BLOCKS ((BATCH * NPTS) / TPB)      // 64
#define R2_BLOCKS ((BATCH * MPTS) / TPB)      // 128
#define R_BLOCKS  (R1_BLOCKS + R2_BLOCKS)     // 192

// ctrl layout (floats): [0..3]=sum dist1 per batch, [4..7]=sum valid dist2,
// [8..11]=nvalid, [15]=ticket (as uint bits)
#define CTRL_FLOATS 16

// vertices [B,3,64,32,64]; take y=31 (last), n = x*64 + z
__device__ __forceinline__ float vtop(const float* __restrict__ v, int b, int c, int n) {
    return v[b * 393216 + c * 131072 + ((n >> 6) << 11) + 1984 + (n & 63)];
}

// ---- pre: build float4 tables {x,y,z, 0.5*||.||^2 (or BIG if padded)} ----
__global__ void __launch_bounds__(TPB) pre_kernel(const float* __restrict__ vert,
                                                  const float* __restrict__ pc,
                                                  float4* __restrict__ vq,
                                                  float4* __restrict__ pq,
                                                  float* __restrict__ ctrl) {
    const int g = blockIdx.x * TPB + threadIdx.x;
    if (g < CTRL_FLOATS) ctrl[g] = 0.0f;           // zero sums + ticket
    if (g < VQ_POINTS) {
        const int b = g >> 12, n = g & (NPTS - 1);
        const float sx = (vtop(vert, b, 0, n) - 0.5f) * 2.0f;
        const float sy = (vtop(vert, b, 1, n) - 0.5f) * 2.0f;
        const float sz = (vtop(vert, b, 2, n) - 0.5f) * 2.0f;
        vq[g] = make_float4(sx, sy, sz, 0.5f * (sx * sx + sy * sy + sz * sz));
    } else {
        const int h = g - VQ_POINTS;
        const int b = h >> 13, m = h & (MPTS - 1);
        const float* pcb = pc + (size_t)b * 3 * MPTS;
        const float qx = pcb[m], qy = pcb[MPTS + m], qz = pcb[2 * MPTS + m];
        const bool valid = !(qx == 0.0f && qy == 0.0f && qz == 0.0f);
        const float w = valid ? 0.5f * (qx * qx + qy * qy + qz * qz) : BIGF;
        pq[h] = make_float4(qx, qy, qz, w);
    }
}

// ---- dist: no LDS; chunk read via block-uniform global loads; min3 pairing ----
__global__ void __launch_bounds__(TPB) dist_kernel(const float4* __restrict__ vq,
                                                   const float4* __restrict__ pq,
                                                   float* __restrict__ part1,
                                                   float* __restrict__ part2) {
    const int tid = threadIdx.x;
    int blk = blockIdx.x;

    if (blk < D1_BLOCKS) {
        // each thread owns 8 v-points; min over a 128-point q chunk
        const int c  = blk % MSPLIT;
        const int nb = (blk / MSPLIT) % D1_NBLK;
        const int b  = blk / (MSPLIT * D1_NBLK);
        const float4* __restrict__ qp = pq + b * MPTS + c * MLEN;
        const int nbase = nb * (TPB * VPT) + tid;
        float* __restrict__ outp = part1 + (size_t)c * (BATCH * NPTS) + (size_t)b * NPTS;

        // runtime skip of all-padding chunks (tail N_PAD region)
        const bool av = (tid < MLEN) && (qp[tid].w != BIGF);
        if (__syncthreads_count(av) == 0) {
#pragma unroll
            for (int k = 0; k < VPT; ++k) outp[nbase + k * TPB] = BIGF;
            return;
        }

        float vx[VPT], vy[VPT], vz[VPT], vv[VPT], best[VPT];
        const float4* __restrict__ vp = vq + b * NPTS;
#pragma unroll
        for (int k = 0; k < VPT; ++k) {
            const float4 t = vp[nbase + k * TPB];
            vx[k] = t.x; vy[k] = t.y; vz[k] = t.z;
            vv[k] = 2.0f * t.w;           // exact: ||v||^2
            best[k] = BIGF;
        }

#pragma unroll 2
        for (int j = 0; j < MLEN; j += 2) {
            const float4 qa = qp[j];
            const float4 qb = qp[j + 1];
#pragma unroll
            for (int k = 0; k < VPT; ++k) {
                // e = 0.5||q||^2 - v.q  (3 fma each); pair -> v_min3
                const float ea = fmaf(-vx[k], qa.x, fmaf(-vy[k], qa.y, fmaf(-vz[k], qa.z, qa.w)));
                const float eb = fmaf(-vx[k], qb.x, fmaf(-vy[k], qb.y, fmaf(-vz[k], qb.z, qb.w)));
                best[k] = fminf(best[k], fminf(ea, eb));
            }
        }

#pragma unroll
        for (int k = 0; k < VPT; ++k)
            outp[nbase + k * TPB] = fmaxf(fmaf(2.0f, best[k], vv[k]), 0.0f);
    } else {
        // each thread owns 8 p-points; min over a 128-point v chunk
        blk -= D1_BLOCKS;
        const int c  = blk % NSPLIT;
        const int mb = (blk / NSPLIT) % D2_MBLK;
        const int b  = blk / (NSPLIT * D2_MBLK);
        const float4* __restrict__ vp = vq + b * NPTS + c * NLEN;
        const float4* __restrict__ qp = pq + b * MPTS;
        const int mbase = mb * (TPB * VPT) + tid;
        float* __restrict__ outp = part2 + (size_t)c * (BATCH * MPTS) + (size_t)b * MPTS;

        float qx[VPT], qy[VPT], qz[VPT], best[VPT];
        bool anyv = false;
#pragma unroll
        for (int k = 0; k < VPT; ++k) {
            const float4 t = qp[mbase + k * TPB];
            qx[k] = t.x; qy[k] = t.y; qz[k] = t.z; best[k] = BIGF;
            anyv = anyv || (t.w != BIGF);
        }
        // owned points all padded -> values are masked out downstream; write 0, exit
        if (__syncthreads_count(anyv) == 0) {
#pragma unroll
            for (int k = 0; k < VPT; ++k) outp[mbase + k * TPB] = 0.0f;
            return;
        }

#pragma unroll 2
        for (int j = 0; j < NLEN; j += 2) {
            const float4 ta = vp[j];
            const float4 tb = vp[j + 1];
#pragma unroll
            for (int k = 0; k < VPT; ++k) {
                const float ea = fmaf(-qx[k], ta.x, fmaf(-qy[k], ta.y, fmaf(-qz[k], ta.z, ta.w)));
                const float eb = fmaf(-qx[k], tb.x, fmaf(-qy[k], tb.y, fmaf(-qz[k], tb.z, tb.w)));
                best[k] = fminf(best[k], fminf(ea, eb));
            }
        }

#pragma unroll
        for (int k = 0; k < VPT; ++k) {
            const float qq = qx[k]*qx[k] + qy[k]*qy[k] + qz[k]*qz[k];
            outp[mbase + k * TPB] = fmaxf(fmaf(2.0f, best[k], qq), 0.0f);
        }
    }
}

// 192 blocks: 0..63 reduce dist1 (1 pt/thread), 64..191 reduce dist2.
// Last block (ticket) finalizes out[0].
__global__ void __launch_bounds__(TPB) reduce_kernel(const float* __restrict__ part1,
                                                     const float* __restrict__ part2,
                                                     const float4* __restrict__ pq,
                                                     float* __restrict__ ctrl,
                                                     float* __restrict__ out) {
    const int tid = threadIdx.x;
    const int wid = tid >> 6;
    __shared__ float rs[4], rc[4];

    float s = 0.0f, cn = 0.0f;
    int b;

    if (blockIdx.x < R1_BLOCKS) {
        const int gid = blockIdx.x * TPB + tid;          // [0, BATCH*NPTS)
        b = gid >> 12;
        float best = BIGF;
#pragma unroll 8
        for (int c = 0; c < MSPLIT; ++c)
            best = fminf(best, part1[(size_t)c * (BATCH * NPTS) + gid]);
        s = best;
    } else {
        const int g2 = (blockIdx.x - R1_BLOCKS) * TPB + tid;  // [0, BATCH*MPTS)
        b = g2 >> 13;
        float best = BIGF;
#pragma unroll 8
        for (int c = 0; c < NSPLIT; ++c)
            best = fminf(best, part2[(size_t)c * (BATCH * MPTS) + g2]);
        const bool v = (pq[g2].w != BIGF);
        s  = v ? best : 0.0f;
        cn = v ? 1.0f : 0.0f;
    }

    // wave reduce (width 64), then cross-wave via LDS
    for (int off = 32; off > 0; off >>= 1) {
        s  += __shfl_down(s, off, 64);
        cn += __shfl_down(cn, off, 64);
    }
    if ((tid & 63) == 0) { rs[wid] = s; rc[wid] = cn; }
    __syncthreads();

    if (tid == 0) {
        const float ts = rs[0] + rs[1] + rs[2] + rs[3];
        if (blockIdx.x < R1_BLOCKS) {
            atomicAdd(&ctrl[b], ts);
        } else {
            atomicAdd(&ctrl[4 + b], ts);
            atomicAdd(&ctrl[8 + b], rc[0] + rc[1] + rc[2] + rc[3]);
        }
        __threadfence();
        const unsigned int old = atomicAdd((unsigned int*)&ctrl[15], 1u);
        if (old == R_BLOCKS - 1) {
            float t = 0.0f;
            for (int bb = 0; bb < BATCH; ++bb) {
                const float s1 = atomicAdd(&ctrl[bb], 0.0f);
                const float s2 = atomicAdd(&ctrl[4 + bb], 0.0f);
                const float nv = atomicAdd(&ctrl[8 + bb], 0.0f);
                t += s1 * (1.0f / (float)NPTS) + s2 / fmaxf(nv, 1.0f);
            }
            out[0] = t * (1.0f / (float)BATCH);
        }
    }
}

extern "C" void kernel_launch(void* const* d_in, const int* in_sizes, int n_in,
                              void* d_out, int out_size, void* d_ws, size_t ws_size,
                              hipStream_t stream) {
    const float* vert = (const float*)d_in[0];
    const float* pc   = (const float*)d_in[1];
    float* out = (float*)d_out;

    float* part1 = (float*)d_ws;
    float* part2 = part1 + PART1_ELEMS;
    float4* vq   = (float4*)(part2 + PART2_ELEMS);
    float4* pq   = vq + VQ_POINTS;
    float* ctrl  = (float*)(pq + PQ_POINTS);   // 16 floats

    pre_kernel<<<(VQ_POINTS + PQ_POINTS) / TPB, TPB, 0, stream>>>(vert, pc, vq, pq, ctrl);
    dist_kernel<<<D1_BLOCKS + D2_BLOCKS, TPB, 0, stream>>>(vq, pq, part1, part2);
    reduce_kernel<<<R_BLOCKS, TPB, 0, stream>>>(part1, part2, pq, ctrl, out);
}

// Round 2
// 89.368 us; speedup vs baseline: 1.2004x; 1.2004x over previous
//
#include <hip/hip_runtime.h>

#define BATCH   4
#define NPTS    4096      // 64*64 top-surface points per batch
#define MPTS    8192      // cloud points per batch
#define TPB     256
#define VPT     8         // points per thread (register tile)
#define MSPLIT  32        // dist1: chunks over M -> MLEN=256
#define NSPLIT  16        // dist2: chunks over N -> NLEN=256
#define MLEN    (MPTS / MSPLIT)           // 256
#define NLEN    (NPTS / NSPLIT)           // 256
#define D1_NBLK (NPTS / (TPB * VPT))      // 2
#define D2_MBLK (MPTS / (TPB * VPT))      // 4
#define D1_BLOCKS (BATCH * D1_NBLK * MSPLIT)  // 256
#define D2_BLOCKS (BATCH * D2_MBLK * NSPLIT)  // 256
#define BIGF    1.0e30f

#define PART1_ELEMS (MSPLIT * BATCH * NPTS)   // 524288 floats (2 MB)
#define PART2_ELEMS (NSPLIT * BATCH * MPTS)   // 524288 floats (2 MB)

// reduce: 1 point per thread -> 192 blocks to stream the partials
#define R1_BLOCKS ((BATCH * NPTS) / TPB)      // 64
#define R2_BLOCKS ((BATCH * MPTS) / TPB)      // 128
#define R_BLOCKS  (R1_BLOCKS + R2_BLOCKS)     // 192

// ctrl layout (floats): [0..3]=sum dist1 per batch, [4..7]=sum valid dist2,
// [8..11]=nvalid, [15]=ticket (as uint bits)
#define CTRL_FLOATS 16

// vertices [B,3,64,32,64]; take y=31 (last), n = x*64 + z
__device__ __forceinline__ float vtop(const float* __restrict__ v, int b, int c, int n) {
    return v[b * 393216 + c * 131072 + ((n >> 6) << 11) + 1984 + (n & 63)];
}

__global__ void __launch_bounds__(TPB) dist_kernel(const float* __restrict__ vert,
                                                   const float* __restrict__ pc,
                                                   float* __restrict__ part1,
                                                   float* __restrict__ part2,
                                                   float* __restrict__ ctrl) {
    __shared__ float4 tile[TPB];
    const int tid = threadIdx.x;
    int blk = blockIdx.x;

    if (blk == 0 && tid < CTRL_FLOATS) ctrl[tid] = 0.0f;   // zeroes sums + ticket

    if (blk < D1_BLOCKS) {
        // ---- dist1: each thread owns 8 v-points; min over a 256-point q chunk ----
        const int c  = blk % MSPLIT;
        const int nb = (blk / MSPLIT) % D1_NBLK;
        const int b  = blk / (MSPLIT * D1_NBLK);
        const float* pcb = pc + (size_t)b * 3 * MPTS;
        const int nbase = nb * (TPB * VPT) + tid;
        float* __restrict__ outp = part1 + (size_t)c * (BATCH * NPTS) + (size_t)b * NPTS;

        bool valid;
        {   // stage q chunk: (qx,qy,qz, 0.5*||q||^2 or BIG if padded)
            const int m = c * MLEN + tid;
            const float qx = pcb[m], qy = pcb[MPTS + m], qz = pcb[2 * MPTS + m];
            valid = !(qx == 0.0f && qy == 0.0f && qz == 0.0f);
            const float qn2 = valid ? 0.5f * (qx * qx + qy * qy + qz * qz) : BIGF;
            tile[tid] = make_float4(qx, qy, qz, qn2);
        }

        // runtime skip: fully-padded chunk contributes only BIG -> sentinel + exit
        // (__syncthreads_count doubles as the staging barrier)
        if (__syncthreads_count(valid) == 0) {
#pragma unroll
            for (int k = 0; k < VPT; ++k) outp[nbase + k * TPB] = BIGF;
            return;
        }

        float vx[VPT], vy[VPT], vz[VPT], best[VPT];
#pragma unroll
        for (int k = 0; k < VPT; ++k) {
            const int n = nbase + k * TPB;
            vx[k] = (vtop(vert, b, 0, n) - 0.5f) * 2.0f;
            vy[k] = (vtop(vert, b, 1, n) - 0.5f) * 2.0f;
            vz[k] = (vtop(vert, b, 2, n) - 0.5f) * 2.0f;
            best[k] = BIGF;
        }

#pragma unroll 2
        for (int j = 0; j < MLEN; j += 2) {
            const float4 qa = tile[j];
            const float4 qb = tile[j + 1];
#pragma unroll
            for (int k = 0; k < VPT; ++k) {
                // e = 0.5||q||^2 - v.q  (3 fma each); pair -> v_min3
                const float ea = fmaf(-vx[k], qa.x, fmaf(-vy[k], qa.y, fmaf(-vz[k], qa.z, qa.w)));
                const float eb = fmaf(-vx[k], qb.x, fmaf(-vy[k], qb.y, fmaf(-vz[k], qb.z, qb.w)));
                best[k] = fminf(best[k], fminf(ea, eb));
            }
        }

#pragma unroll
        for (int k = 0; k < VPT; ++k) {
            const float vv = vx[k]*vx[k] + vy[k]*vy[k] + vz[k]*vz[k];
            outp[nbase + k * TPB] = fmaxf(fmaf(2.0f, best[k], vv), 0.0f);
        }
    } else {
        // ---- dist2: each thread owns 8 p-points; min over a 256-point v chunk ----
        blk -= D1_BLOCKS;
        const int c  = blk % NSPLIT;
        const int mb = (blk / NSPLIT) % D2_MBLK;
        const int b  = blk / (NSPLIT * D2_MBLK);
        const float* pcb = pc + (size_t)b * 3 * MPTS;
        const int mbase = mb * (TPB * VPT) + tid;
        float* __restrict__ outp = part2 + (size_t)c * (BATCH * MPTS) + (size_t)b * MPTS;

        {   // stage v chunk: (vx,vy,vz, 0.5*||v||^2)
            const int n = c * NLEN + tid;
            const float sx = (vtop(vert, b, 0, n) - 0.5f) * 2.0f;
            const float sy = (vtop(vert, b, 1, n) - 0.5f) * 2.0f;
            const float sz = (vtop(vert, b, 2, n) - 0.5f) * 2.0f;
            tile[tid] = make_float4(sx, sy, sz, 0.5f * (sx*sx + sy*sy + sz*sz));
        }

        float qx[VPT], qy[VPT], qz[VPT], best[VPT];
        bool anyv = false;
#pragma unroll
        for (int k = 0; k < VPT; ++k) {
            const int m = mbase + k * TPB;
            qx[k] = pcb[m];
            qy[k] = pcb[MPTS + m];
            qz[k] = pcb[2 * MPTS + m];
            best[k] = BIGF;
            anyv = anyv || !(qx[k] == 0.0f && qy[k] == 0.0f && qz[k] == 0.0f);
        }
        // owned points all padded -> every output of this block is masked out
        // downstream (reduce applies v ? best : 0), so skip entirely.
        // (__syncthreads_count doubles as the staging barrier)
        if (__syncthreads_count(anyv) == 0) return;

#pragma unroll 2
        for (int j = 0; j < NLEN; j += 2) {
            const float4 ta = tile[j];
            const float4 tb = tile[j + 1];
#pragma unroll
            for (int k = 0; k < VPT; ++k) {
                const float ea = fmaf(-qx[k], ta.x, fmaf(-qy[k], ta.y, fmaf(-qz[k], ta.z, ta.w)));
                const float eb = fmaf(-qx[k], tb.x, fmaf(-qy[k], tb.y, fmaf(-qz[k], tb.z, tb.w)));
                best[k] = fminf(best[k], fminf(ea, eb));
            }
        }

#pragma unroll
        for (int k = 0; k < VPT; ++k) {
            const float qq = qx[k]*qx[k] + qy[k]*qy[k] + qz[k]*qz[k];
            outp[mbase + k * TPB] = fmaxf(fmaf(2.0f, best[k], qq), 0.0f);
        }
    }
}

// 192 blocks: 0..63 reduce dist1 (1 pt/thread), 64..191 reduce dist2.
// Last block (ticket) finalizes out[0].
__global__ void __launch_bounds__(TPB) reduce_kernel(const float* __restrict__ part1,
                                                     const float* __restrict__ part2,
                                                     const float* __restrict__ pc,
                                                     float* __restrict__ ctrl,
                                                     float* __restrict__ out) {
    const int tid = threadIdx.x;
    const int wid = tid >> 6;
    __shared__ float rs[4], rc[4];

    float s = 0.0f, cn = 0.0f;
    int b;

    if (blockIdx.x < R1_BLOCKS) {
        const int gid = blockIdx.x * TPB + tid;          // [0, BATCH*NPTS)
        b = gid >> 12;
        float best = BIGF;
#pragma unroll
        for (int c = 0; c < MSPLIT; c += 2)
            best = fminf(best, fminf(part1[(size_t)c * (BATCH * NPTS) + gid],
                                     part1[(size_t)(c + 1) * (BATCH * NPTS) + gid]));
        s = best;
    } else {
        const int g2 = (blockIdx.x - R1_BLOCKS) * TPB + tid;  // [0, BATCH*MPTS)
        b = g2 >> 13;
        const int m = g2 & (MPTS - 1);
        float best = BIGF;
#pragma unroll
        for (int c = 0; c < NSPLIT; c += 2)
            best = fminf(best, fminf(part2[(size_t)c * (BATCH * MPTS) + g2],
                                     part2[(size_t)(c + 1) * (BATCH * MPTS) + g2]));
        const float* pcb = pc + (size_t)b * 3 * MPTS;
        const float qx = pcb[m], qy = pcb[MPTS + m], qz = pcb[2 * MPTS + m];
        const bool v = !(qx == 0.0f && qy == 0.0f && qz == 0.0f);
        s  = v ? best : 0.0f;
        cn = v ? 1.0f : 0.0f;
    }

    // wave reduce (width 64), then cross-wave via LDS
    for (int off = 32; off > 0; off >>= 1) {
        s  += __shfl_down(s, off, 64);
        cn += __shfl_down(cn, off, 64);
    }
    if ((tid & 63) == 0) { rs[wid] = s; rc[wid] = cn; }
    __syncthreads();

    if (tid == 0) {
        const float ts = rs[0] + rs[1] + rs[2] + rs[3];
        if (blockIdx.x < R1_BLOCKS) {
            atomicAdd(&ctrl[b], ts);
        } else {
            atomicAdd(&ctrl[4 + b], ts);
            atomicAdd(&ctrl[8 + b], rc[0] + rc[1] + rc[2] + rc[3]);
        }
        __threadfence();
        const unsigned int old = atomicAdd((unsigned int*)&ctrl[15], 1u);
        if (old == R_BLOCKS - 1) {
            // last block: all sums are globally visible; read via atomic RMW
            float t = 0.0f;
            for (int bb = 0; bb < BATCH; ++bb) {
                const float s1 = atomicAdd(&ctrl[bb], 0.0f);
                const float s2 = atomicAdd(&ctrl[4 + bb], 0.0f);
                const float nv = atomicAdd(&ctrl[8 + bb], 0.0f);
                t += s1 * (1.0f / (float)NPTS) + s2 / fmaxf(nv, 1.0f);
            }
            out[0] = t * (1.0f / (float)BATCH);
        }
    }
}

extern "C" void kernel_launch(void* const* d_in, const int* in_sizes, int n_in,
                              void* d_out, int out_size, void* d_ws, size_t ws_size,
                              hipStream_t stream) {
    const float* vert = (const float*)d_in[0];
    const float* pc   = (const float*)d_in[1];
    float* out = (float*)d_out;

    float* part1 = (float*)d_ws;
    float* part2 = part1 + PART1_ELEMS;
    float* ctrl  = part2 + PART2_ELEMS;   // 16 floats

    dist_kernel<<<D1_BLOCKS + D2_BLOCKS, TPB, 0, stream>>>(vert, pc, part1, part2, ctrl);
    reduce_kernel<<<R_BLOCKS, TPB, 0, stream>>>(part1, part2, pc, ctrl, out);
}